// Round 12
// baseline (386.012 us; speedup 1.0000x reference)
//
#include <hip/hip_runtime.h>
#include <hip/hip_bf16.h>
#include <math.h>

// ---------------------------------------------------------------------------
// GATv2 2-layer + linear head, MI355X (gfx950)
// Round 12: fixed-stride CSR -- the scan and scatter phases are eliminated.
//   - hist_csr_prep: r = atomicAdd(&deg[dst],1); r<64 -> csr[dst*64+r]=src
//     directly (the rank IS the slot); r>=64 -> tiny overflow list (device
//     atomic counter; Poisson(16) => ~never taken, kept for correctness).
//   - deg_block_reduce / deg_scan_apply / scatter: GONE (offsets unused).
//   - gat_node reads deg[node] directly; j0 = node*64. deg>64 edges come
//     from a wave-uniform scan of the overflow list (cold path).
//   Pipeline: memset, hist_csr||prep, gemm1, gat1, gemm2, gat2, final (8
//   dispatches incl. memsets, was 10).
// gemm_dual / gat fast path / final_linear: round-6 proven bodies unchanged.
// ---------------------------------------------------------------------------

#define IN_DIM 256
#define HIDHC 256   // HEADS*HID
#define HID 64
#define OUT_DIM 40

using half8  = __attribute__((ext_vector_type(8))) _Float16;
using half4  = __attribute__((ext_vector_type(4))) _Float16;
using half2v = __attribute__((ext_vector_type(2))) _Float16;
using f32x4  = __attribute__((ext_vector_type(4))) float;

__device__ __forceinline__ void gload16(const void* g, void* l) {
    __builtin_amdgcn_global_load_lds(
        (const __attribute__((address_space(1))) void*)g,
        (__attribute__((address_space(3))) void*)l, 16, 0, 0);
}

// -------------------- phase 1: hist+fixed-CSR || input prep -----------------
// Packed A layout: (node,k) -> (node>>7)*32768 + (k>>3)*1024 + (node&127)*8 + (k&7)
// Packed W layout: (n,k) -> (n>>7)*32768 + (k>>5)*4096 + ((k>>3)&3)*1024
//                           + (n&127)*8 + (k&7)
__global__ void hist_csr_prep(const int* __restrict__ src, const int* __restrict__ dst,
                              int* __restrict__ deg, int* __restrict__ csr,
                              int* __restrict__ oflow_cnt, int* __restrict__ oflow,
                              int E, int nbh,
                              const float* __restrict__ x, _Float16* __restrict__ Af,
                              const float* __restrict__ W0, const float* __restrict__ W1,
                              const float* __restrict__ W2, const float* __restrict__ W3,
                              _Float16* __restrict__ T, int n4, int nb_cvt) {
    int bid = blockIdx.x;
    if (bid < nbh) {                       // histogram + direct CSR placement
        int i = bid * 256 + threadIdx.x;
        if (i < E) {
            int d = dst[i];
            int r = atomicAdd(&deg[d], 1);
            if (r < 64) {
                csr[d * 64 + r] = src[i];
            } else {                       // overflow (deg>64): rare, correct
                int q = atomicAdd(oflow_cnt, 1);
                oflow[2 * q] = d;
                oflow[2 * q + 1] = src[i];
            }
        }
    } else if (bid < nbh + nb_cvt) {       // x fp32 -> fp16 packed
        int i = (bid - nbh) * 256 + threadIdx.x;
        if (i >= n4) return;
        float4 v = ((const float4*)x)[i];
        half4 h = { (_Float16)v.x, (_Float16)v.y, (_Float16)v.z, (_Float16)v.w };
        int node = i >> 6;
        int kb = (i & 63) * 4;
        size_t a = (size_t)(node >> 7) * 32768 + (size_t)(kb >> 3) * 1024
                 + (size_t)(node & 127) * 8 + (kb & 7);
        *(half4*)(Af + a) = h;
    } else {                               // weight transpose+pack
        int widx = bid - nbh - nb_cvt;
        int wsel = widx >> 8, k = widx & 255, nn = threadIdx.x;
        const float* Wsel = (wsel == 0) ? W0 : (wsel == 1) ? W1
                          : (wsel == 2) ? W2 : W3;
        float v = Wsel[k * 256 + nn];
        size_t a = (size_t)wsel * 65536
                 + (size_t)(nn >> 7) * 32768 + (size_t)(k >> 5) * 4096
                 + (size_t)((k >> 3) & 3) * 1024 + (size_t)(nn & 127) * 8 + (k & 7);
        T[a] = (_Float16)v;
    }
}

// -------------------- dual MFMA GEMM tile (device body, round-6 proven) -----

__device__ __forceinline__ void gemm_tile(
    const _Float16* __restrict__ Apk,
    const _Float16* __restrict__ W0, const float* __restrict__ b0, _Float16* __restrict__ C0,
    const _Float16* __restrict__ W1, const float* __restrict__ b1, _Float16* __restrict__ C1,
    int M, int bx, int by, _Float16* sA, _Float16* sW)
{
    int tid = threadIdx.x;
    int bm = bx * 128;
    int bn = by * 128;

    int lane = tid & 63, w = tid >> 6;       // 8 waves
    int z  = w >> 2, wq = w & 3;
    int r = lane & 15, q = lane >> 4;
    int m0 = (wq >> 1) * 64, n0 = (wq & 1) * 64;

    const _Float16* Abase = Apk + (size_t)bx * 32768;
    const _Float16* W0b   = W0  + (size_t)by * 32768;
    const _Float16* W1b   = W1  + (size_t)by * 32768;
    int go = tid * 8;                        // granule offset (elements)

    f32x4 acc[4][4];
    #pragma unroll
    for (int i = 0; i < 4; ++i)
        #pragma unroll
        for (int j = 0; j < 4; ++j) acc[i][j] = (f32x4)0.f;

    gload16(Abase + go, sA + go);
    gload16(W0b + go, sW + go);
    gload16(W1b + go, sW + 4096 + go);
    __builtin_amdgcn_s_waitcnt(0);   // drain LDS-DMA
    __syncthreads();

    #pragma unroll 1
    for (int kt = 0; kt < 8; ++kt) {
        int buf = kt & 1;
        if (kt < 7) {
            int k0 = (kt + 1) * 4096;
            gload16(Abase + k0 + go, sA + (buf ^ 1) * 4096 + go);
            gload16(W0b + k0 + go, sW + ((buf ^ 1) * 2 + 0) * 4096 + go);
            gload16(W1b + k0 + go, sW + ((buf ^ 1) * 2 + 1) * 4096 + go);
        }
        half8 a[4], b[4];
        #pragma unroll
        for (int i = 0; i < 4; ++i) {
            a[i] = *(const half8*)(sA + buf * 4096 + (q * 128 + m0 + i * 16 + r) * 8);
            b[i] = *(const half8*)(sW + (buf * 2 + z) * 4096 + (q * 128 + n0 + i * 16 + r) * 8);
        }
        #pragma unroll
        for (int i = 0; i < 4; ++i)
            #pragma unroll
            for (int j = 0; j < 4; ++j)
                acc[i][j] = __builtin_amdgcn_mfma_f32_16x16x32_f16(a[i], b[j], acc[i][j], 0, 0, 0);
        __builtin_amdgcn_s_waitcnt(0);   // drain prefetch DMA before buffer swap
        __syncthreads();
    }

    const float* bias = z ? b1 : b0;
    _Float16*    C    = z ? C1 : C0;

    float bv[4];
    #pragma unroll
    for (int j = 0; j < 4; ++j) bv[j] = bias[bn + n0 + j * 16 + r];
    #pragma unroll
    for (int i = 0; i < 4; ++i) {
        #pragma unroll
        for (int reg = 0; reg < 4; ++reg) {
            int orow = bm + m0 + i * 16 + q * 4 + reg;
            if (orow < M) {
                #pragma unroll
                for (int j = 0; j < 4; ++j)
                    C[(size_t)orow * 256 + bn + n0 + j * 16 + r] =
                        (_Float16)(acc[i][j][reg] + bv[j]);
            }
        }
    }
}

__global__ __launch_bounds__(512) void gemm_dual(
    const _Float16* __restrict__ Apk,
    const _Float16* __restrict__ W0, const float* __restrict__ b0, _Float16* __restrict__ C0,
    const _Float16* __restrict__ W1, const float* __restrict__ b1, _Float16* __restrict__ C1,
    int M)
{
    __shared__ __align__(16) _Float16 sA[2 * 4096];
    __shared__ __align__(16) _Float16 sW[2 * 2 * 4096];
    gemm_tile(Apk, W0, b0, C0, W1, b1, C1, M, blockIdx.x, blockIdx.y, sA, sW);
}

// -------------------- GAT node kernel: half-wave-per-edge ---------------------
// 1 node/wave, 12500 blocks. Fixed-stride CSR: adjacency = csr[node*64 + 0..
// min(deg,64)). Adjacency row preloaded into idxv (1 coalesced load); per-pair
// src via __shfl. Depth-2 named-slot gather pipeline. deg>64 -> overflow-list
// scan (wave-uniform, cold). mode 0 writes PACKED layout (next gemm's A).

__global__ __launch_bounds__(256) void gat_node(
    const _Float16* __restrict__ xl, const _Float16* __restrict__ xr,
    const float* __restrict__ att, const float* __restrict__ bias,
    const int* __restrict__ degv, const int* __restrict__ csr_src,
    const int* __restrict__ oflow_cnt, const int* __restrict__ oflow,
    void* __restrict__ out0, int n, int mode)
{
    int wid = threadIdx.x >> 6;
    int node = (blockIdx.x << 2) + wid;
    if (node >= n) return;
    int lane = threadIdx.x & 63;
    int H = lane >> 5;
    int p = lane & 31;

    const half2v c02 = { (_Float16)0.2f, (_Float16)0.2f };

    half8 xrh = *(const half8*)(xr + (size_t)node * HIDHC + p * 8);
    half2v xr01 = __builtin_shufflevector(xrh, xrh, 0, 1);
    half2v xr23 = __builtin_shufflevector(xrh, xrh, 2, 3);
    half2v xr45 = __builtin_shufflevector(xrh, xrh, 4, 5);
    half2v xr67 = __builtin_shufflevector(xrh, xrh, 6, 7);

    float4 af0 = *(const float4*)(att + p * 8);
    float4 af1 = *(const float4*)(att + p * 8 + 4);
    half2v at01 = { (_Float16)af0.x, (_Float16)af0.y };
    half2v at23 = { (_Float16)af0.z, (_Float16)af0.w };
    half2v at45 = { (_Float16)af1.x, (_Float16)af1.y };
    half2v at67 = { (_Float16)af1.z, (_Float16)af1.w };

    float acc[8];
    #pragma unroll
    for (int k = 0; k < 8; ++k) acc[k] = 0.f;
    float d = 0.f;

    // pair compute: both half-waves carry a (different) edge row h
    auto edge_compute = [&](half8 h) {
        half2v h01 = __builtin_shufflevector(h, h, 0, 1);
        half2v h23 = __builtin_shufflevector(h, h, 2, 3);
        half2v h45 = __builtin_shufflevector(h, h, 4, 5);
        half2v h67 = __builtin_shufflevector(h, h, 6, 7);
        half2v s01 = h01 + xr01, s23 = h23 + xr23, s45 = h45 + xr45, s67 = h67 + xr67;
        half2v l01 = __builtin_elementwise_max(s01, s01 * c02);
        half2v l23 = __builtin_elementwise_max(s23, s23 * c02);
        half2v l45 = __builtin_elementwise_max(s45, s45 * c02);
        half2v l67 = __builtin_elementwise_max(s67, s67 * c02);
        float e = __builtin_amdgcn_fdot2(l01, at01, 0.f, false);
        e = __builtin_amdgcn_fdot2(l23, at23, e, false);
        e = __builtin_amdgcn_fdot2(l45, at45, e, false);
        e = __builtin_amdgcn_fdot2(l67, at67, e, false);
        e += __shfl_xor(e, 1);
        e += __shfl_xor(e, 2);
        e += __shfl_xor(e, 4);
        float pw = __expf(e);
        d += pw;
        #pragma unroll
        for (int k = 0; k < 8; ++k) acc[k] = fmaf(pw, (float)h[k], acc[k]);
    };
    // single-edge compute: only H==0 half contributes
    auto edge_compute_single = [&](half8 h) {
        half2v h01 = __builtin_shufflevector(h, h, 0, 1);
        half2v h23 = __builtin_shufflevector(h, h, 2, 3);
        half2v h45 = __builtin_shufflevector(h, h, 4, 5);
        half2v h67 = __builtin_shufflevector(h, h, 6, 7);
        half2v s01 = h01 + xr01, s23 = h23 + xr23, s45 = h45 + xr45, s67 = h67 + xr67;
        half2v l01 = __builtin_elementwise_max(s01, s01 * c02);
        half2v l23 = __builtin_elementwise_max(s23, s23 * c02);
        half2v l45 = __builtin_elementwise_max(s45, s45 * c02);
        half2v l67 = __builtin_elementwise_max(s67, s67 * c02);
        float e = __builtin_amdgcn_fdot2(l01, at01, 0.f, false);
        e = __builtin_amdgcn_fdot2(l23, at23, e, false);
        e = __builtin_amdgcn_fdot2(l45, at45, e, false);
        e = __builtin_amdgcn_fdot2(l67, at67, e, false);
        e += __shfl_xor(e, 1);
        e += __shfl_xor(e, 2);
        e += __shfl_xor(e, 4);
        float pw = (H == 0) ? __expf(e) : 0.f;
        d += pw;
        #pragma unroll
        for (int k = 0; k < 8; ++k) acc[k] = fmaf(pw, (float)h[k], acc[k]);
    };

    int dg = __builtin_amdgcn_readfirstlane(degv[node]);
    int j0 = node << 6;                  // fixed stride 64

    // --- fast path: adjacency row in one register (deg<=64 slots) ---
    int fast = min(dg, 64);
    int npf = fast >> 1;                 // pairs handled by the pipeline
    int idxv = 0;
    if (lane < fast) idxv = csr_src[j0 + lane];

    half8 hA, hB;                        // depth-2, named slots (no rotation)
    if (npf > 0) { int s = __shfl(idxv, 0 + H, 64); hA = *(const half8*)(xl + (size_t)s * HIDHC + p * 8); }
    if (npf > 1) { int s = __shfl(idxv, 2 + H, 64); hB = *(const half8*)(xl + (size_t)s * HIDHC + p * 8); }
    int t = 0;
    for (; t + 4 <= npf; t += 2) {       // steady state: compute 2, prefetch 2
        half8 ha = hA, hb = hB;
        { int s = __shfl(idxv, (t + 2) * 2 + H, 64); hA = *(const half8*)(xl + (size_t)s * HIDHC + p * 8); }
        { int s = __shfl(idxv, (t + 3) * 2 + H, 64); hB = *(const half8*)(xl + (size_t)s * HIDHC + p * 8); }
        edge_compute(ha);
        edge_compute(hb);
    }
    if (t + 2 <= npf) {                  // 2 or 3 pairs left
        half8 ha = hA, hb = hB;
        if (t + 2 < npf) { int s = __shfl(idxv, (t + 2) * 2 + H, 64); hA = *(const half8*)(xl + (size_t)s * HIDHC + p * 8); }
        edge_compute(ha);
        edge_compute(hb);
        t += 2;
    }
    if (t < npf) {                       // final pair
        edge_compute(hA);
    }
    if (fast & 1) {                      // odd leftover edge (slot fast-1)
        int s0 = __shfl(idxv, fast - 1, 64);
        half8 h = *(const half8*)(xl + (size_t)s0 * HIDHC + p * 8);
        edge_compute_single(h);
    }

    // --- overflow path: deg>64 (rare; wave-uniform scan of global list) ---
    if (dg > 64) {
        int cnt = __builtin_amdgcn_readfirstlane(oflow_cnt[0]);
        for (int k = 0; k < cnt; ++k) {
            int dd = __builtin_amdgcn_readfirstlane(oflow[2 * k]);
            if (dd == node) {
                int ss = __builtin_amdgcn_readfirstlane(oflow[2 * k + 1]);
                half8 h = *(const half8*)(xl + (size_t)ss * HIDHC + p * 8);
                edge_compute_single(h);
            }
        }
    }

    d += __shfl_xor(d, 32);
    #pragma unroll
    for (int k = 0; k < 8; ++k) acc[k] += __shfl_xor(acc[k], 32);

    float inv = 1.f / (d + 1e-16f);
    float o[8];
    #pragma unroll
    for (int k = 0; k < 8; ++k) o[k] = acc[k] * inv;

    if (mode == 0) {
        if (H == 0) {
            float4 b0 = *(const float4*)(bias + p * 8);
            float4 b1 = *(const float4*)(bias + p * 8 + 4);
            float bb[8] = { b0.x, b0.y, b0.z, b0.w, b1.x, b1.y, b1.z, b1.w };
            half8 hh;
            #pragma unroll
            for (int k = 0; k < 8; ++k) hh[k] = (_Float16)fmaxf(o[k] + bb[k], 0.f);
            // packed layout write: next gemm's A ([tile][kgroup=p][row][8])
            _Float16* dstp = (_Float16*)out0 + (size_t)(node >> 7) * 32768
                           + (size_t)p * 1024 + (size_t)(node & 127) * 8;
            *(half8*)dstp = hh;
        }
    } else {
        #pragma unroll
        for (int k = 0; k < 8; ++k) {
            o[k] += __shfl_xor(o[k], 8);
            o[k] += __shfl_xor(o[k], 16);
        }
        if (lane < 8) {
            float4 b0 = *(const float4*)(bias + p * 8);
            float4 b1 = *(const float4*)(bias + p * 8 + 4);
            float bb[8] = { b0.x, b0.y, b0.z, b0.w, b1.x, b1.y, b1.z, b1.w };
            float4 o0, o1;
            o0.x = fmaxf(o[0] * 0.25f + bb[0], 0.f);
            o0.y = fmaxf(o[1] * 0.25f + bb[1], 0.f);
            o0.z = fmaxf(o[2] * 0.25f + bb[2], 0.f);
            o0.w = fmaxf(o[3] * 0.25f + bb[3], 0.f);
            o1.x = fmaxf(o[4] * 0.25f + bb[4], 0.f);
            o1.y = fmaxf(o[5] * 0.25f + bb[5], 0.f);
            o1.z = fmaxf(o[6] * 0.25f + bb[6], 0.f);
            o1.w = fmaxf(o[7] * 0.25f + bb[7], 0.f);
            float* dstp = (float*)out0 + (size_t)node * HID + p * 8;
            *(float4*)dstp = o0;
            *(float4*)(dstp + 4) = o1;
        }
    }
}

// -------------------- final linear: out[N,40] = h2[N,64] @ Wc[64,40] + bc --------------------

__global__ __launch_bounds__(256) void final_linear(
    const float* __restrict__ h2, const float* __restrict__ Wc,
    const float* __restrict__ bc, float* __restrict__ out, int n)
{
    __shared__ float Ws[HID * OUT_DIM];
    __shared__ float bs[OUT_DIM];
    __shared__ float hs[64][HID + 1];

    for (int i = threadIdx.x; i < HID * OUT_DIM; i += 256) Ws[i] = Wc[i];
    if (threadIdx.x < OUT_DIM) bs[threadIdx.x] = bc[threadIdx.x];

    int n0 = blockIdx.x * 64;
    for (int i = threadIdx.x; i < 64 * HID; i += 256) {
        int r = i >> 6, c = i & 63;
        int node = n0 + r;
        hs[r][c] = (node < n) ? h2[(size_t)node * HID + c] : 0.f;
    }
    __syncthreads();

    for (int idx = threadIdx.x; idx < 64 * OUT_DIM; idx += 256) {
        int r = idx / OUT_DIM, o = idx % OUT_DIM;
        int node = n0 + r;
        if (node < n) {
            float s = bs[o];
            #pragma unroll
            for (int c = 0; c < HID; ++c) s = fmaf(hs[r][c], Ws[c * OUT_DIM + o], s);
            out[(size_t)node * OUT_DIM + o] = s;
        }
    }
}

// -------------------- launch --------------------

extern "C" void kernel_launch(void* const* d_in, const int* in_sizes, int n_in,
                              void* d_out, int out_size, void* d_ws, size_t ws_size,
                              hipStream_t stream) {
    const int N = in_sizes[0] / IN_DIM;   // 50000
    const int E = in_sizes[1];            // 800000

    const float* x    = (const float*)d_in[0];
    const int*   src  = (const int*)d_in[1];
    const int*   dst  = (const int*)d_in[2];
    const float* Wl1  = (const float*)d_in[3];
    const float* bl1  = (const float*)d_in[4];
    const float* Wr1  = (const float*)d_in[5];
    const float* br1  = (const float*)d_in[6];
    const float* att1 = (const float*)d_in[7];
    const float* bias1= (const float*)d_in[8];
    const float* Wl2  = (const float*)d_in[9];
    const float* bl2  = (const float*)d_in[10];
    const float* Wr2  = (const float*)d_in[11];
    const float* br2  = (const float*)d_in[12];
    const float* att2 = (const float*)d_in[13];
    const float* bias2= (const float*)d_in[14];
    const float* Wc   = (const float*)d_in[15];
    const float* bc   = (const float*)d_in[16];

    char* ws = (char*)d_ws;
    size_t off = 0;
    const int NT = (N + 127) / 128;                                   // A tiles
    _Float16* xlh = (_Float16*)(ws + off); off += (size_t)N * HIDHC * 2;  // xl fp16 (row-major)
    _Float16* xrh = (_Float16*)(ws + off); off += (size_t)N * HIDHC * 2;  // xr fp16 (row-major)
    _Float16* Af  = (_Float16*)(ws + off); off += (size_t)NT * 32768 * 2; // x / h1 fp16 (PACKED)
    float*    h2  = (float*)(ws + off);    off += (size_t)N * HID * 4;
    _Float16* Wt  = (_Float16*)(ws + off); off += (size_t)4 * 65536 * 2;  // packed weights
    int* deg      = (int*)(ws + off); off += (size_t)N * 4;
    int* oflow_cnt= (int*)(ws + off); off += 4;                            // adjacent to deg
    int* csr      = (int*)(ws + off); off += (size_t)N * 64 * 4;           // fixed stride
    int* oflow    = (int*)(ws + off); off += (size_t)E * 2 * 4;            // worst case

    // phase 0: zero deg + oflow_cnt (+ packed-A tail tile once)
    hipMemsetAsync(deg, 0, ((size_t)N + 1) * 4, stream);
    if (N & 127)
        hipMemsetAsync(Af + (size_t)(NT - 1) * 32768, 0, 32768 * 2, stream);

    // phase 1: histogram + fixed-CSR placement || input prep (one dispatch)
    const int nbh = (E + 255) / 256;
    const int n4 = N * HIDHC / 4;
    const int nb_cvt = (n4 + 255) / 256;
    hist_csr_prep<<<nbh + nb_cvt + 1024, 256, 0, stream>>>(
        src, dst, deg, csr, oflow_cnt, oflow, E, nbh,
        x, Af, Wl1, Wr1, Wl2, Wr2, Wt, n4, nb_cvt);

    const int KW = 65536;
    // layer 1
    gemm_dual<<<dim3(NT, 2), 512, 0, stream>>>(Af,
        Wt + 0 * KW, bl1, xlh,
        Wt + 1 * KW, br1, xrh, N);
    gat_node<<<(N + 3) / 4, 256, 0, stream>>>(xlh, xrh, att1, bias1, deg, csr,
                                              oflow_cnt, oflow, (void*)Af, N, 0);
    // layer 2
    gemm_dual<<<dim3(NT, 2), 512, 0, stream>>>(Af,
        Wt + 2 * KW, bl2, xlh,
        Wt + 3 * KW, br2, xrh, N);
    gat_node<<<(N + 3) / 4, 256, 0, stream>>>(xlh, xrh, att2, bias2, deg, csr,
                                              oflow_cnt, oflow, (void*)h2, N, 1);
    // head
    final_linear<<<(N + 63) / 64, 256, 0, stream>>>(h2, Wc, bc, (float*)d_out, N);
}